// Round 7
// baseline (2270.428 us; speedup 1.0000x reference)
//
#include <hip/hip_runtime.h>

#define HH   512
#define WW   512
#define CIN  16
#define COUT 16
#define KK   5

#define TLW  256          // output tile width
#define TLH  4            // output tile height
#define SR   8            // staged rows = TLH + 4 halo
#define SC   264          // 4 pad | 256 body | 4 pad (body at col 4, 16B-aligned)
#define NW   (CIN * KK * COUT)   // 1280 weights

__device__ __forceinline__ void gll16(const float* g, float* l) {
    __builtin_amdgcn_global_load_lds(
        (const __attribute__((address_space(1))) unsigned int*)g,
        (__attribute__((address_space(3))) unsigned int*)l, 16, 0, 0);
}

// out[n,o,h,w] = sum_i sum_d fw[o,i,d+2] * x[n,i,h+d,w+d]   (zero pad)
// Block (64,4): 256x4 output tile, all 16 output channels.
// Double-buffered LDS x-tile staged via global_load_lds; weights transposed
// into LDS once ([i][d][o] layout) so the inner loop has NO scalar loads:
// all lgkmcnt traffic is in-order DS ops -> precise lgkmcnt(N) scheduling.
__global__ __launch_bounds__(256, 4) void diag_conv_kernel(
    const float* __restrict__ x, const float* __restrict__ fw,
    float* __restrict__ out)
{
    __shared__ float tile[2][SR][SC];
    __shared__ float wlds[NW];                // [i][d][o], 5 KiB

    const int tx  = threadIdx.x;              // 0..63 (= lane)
    const int ty  = threadIdx.y;              // 0..3  (= wave)
    const int tid = (ty << 6) | tx;

    // one-time weight transpose: wlds[(i*5+d)*16+o] = fw[(o*16+i)*5+d]
    for (int s = tid; s < NW; s += 256) {
        const int i = s / (KK * COUT);
        const int r = s - i * (KK * COUT);
        const int d = r >> 4;
        const int o = r & 15;
        wlds[s] = fw[(o * CIN + i) * KK + d];
    }

    // XCD-chunked bijective swizzle (4096 % 8 == 0): vertical neighbors share an XCD L2.
    const int id  = blockIdx.x;
    const int nid = (id & 7) * 512 + (id >> 3);
    const int n   = nid >> 8;
    const int rem = nid & 255;
    const int bh  = rem >> 1;                 // 0..127
    const int bx  = rem & 1;                  // 0..1

    const int h  = bh * TLH + ty;
    const int c0 = bx * TLW;

    const float* xn = x + (size_t)n * (CIN * HH * WW);

    // body staging: wave ty stages rows {ty, ty+4}; one gll16 each (64 lanes x 16B)
    const int  r0   = ty, r1 = ty + 4;
    const int  gr0  = bh * TLH - 2 + r0;
    const int  gr1  = bh * TLH - 2 + r1;
    const bool rok0 = (unsigned)gr0 < (unsigned)HH;   // wave-uniform
    const bool rok1 = (unsigned)gr1 < (unsigned)HH;
    const int  bo0  = gr0 * WW + c0 + tx * 4;         // per-lane float offset
    const int  bo1  = gr1 * WW + c0 + tx * 4;

    // halo cols (2 left + 2 right) x 8 rows = 32 values: first 32 lanes, register path
    int  hr = 0, hlc = 0, hoff = 0; bool hok = false;
    if (tid < 32) {
        hr = tid >> 2; const int k = tid & 3;
        hlc = (k < 2) ? (2 + k) : (258 + k);                    // LDS col 2,3,260,261
        const int gc = (k < 2) ? (c0 - 2 + k) : (c0 + 254 + k); // global col
        const int gr = bh * TLH - 2 + hr;
        hok  = ((unsigned)gr < (unsigned)HH) & ((unsigned)gc < (unsigned)WW);
        hoff = hok ? (gr * WW + gc) : 0;
    }

    float acc[COUT][4];
#pragma unroll
    for (int o = 0; o < COUT; ++o)
#pragma unroll
        for (int p = 0; p < 4; ++p) acc[o][p] = 0.f;

    auto stage = [&](int i, float (*T)[SC]) {
        const float* xi = xn + i * (HH * WW);
        if (rok0) gll16(xi + bo0, &T[r0][4]);     // uniform LDS base + lane*16
        else { float4 z{0.f, 0.f, 0.f, 0.f};
               *reinterpret_cast<float4*>(&T[r0][4 + tx * 4]) = z; }
        if (rok1) gll16(xi + bo1, &T[r1][4]);
        else { float4 z{0.f, 0.f, 0.f, 0.f};
               *reinterpret_cast<float4*>(&T[r1][4 + tx * 4]) = z; }
    };
    auto halo_load = [&](int i) -> float {        // issue early...
        float v = 0.f;
        if (tid < 32) { const float t = xn[i * (HH * WW) + hoff]; v = hok ? t : 0.f; }
        return v;
    };
    auto halo_write = [&](float (*T)[SC], float v) {  // ...write late (after compute)
        if (tid < 32) T[hr][hlc] = v;
    };

    auto compute = [&](int i, const float (*T)[SC]) {
#pragma unroll
        for (int d = -2; d <= 2; ++d) {
            // row ty+d+2 in [0,7]; cols tx+p*64+d+4 in [2,261]
            const float* Tr = &T[ty + d + 2][tx + d + 4];
            const float v0 = Tr[0], v1 = Tr[64], v2 = Tr[128], v3 = Tr[192];
            // 16 contiguous weights, uniform address -> broadcast ds_read_b128 x4
            const float* wp = &wlds[(i * KK + (d + 2)) * COUT];
            float wt[COUT];
#pragma unroll
            for (int o = 0; o < COUT; ++o) wt[o] = wp[o];
#pragma unroll
            for (int o = 0; o < COUT; ++o) {
                acc[o][0] = fmaf(wt[o], v0, acc[o][0]);
                acc[o][1] = fmaf(wt[o], v1, acc[o][1]);
                acc[o][2] = fmaf(wt[o], v2, acc[o][2]);
                acc[o][3] = fmaf(wt[o], v3, acc[o][3]);
            }
        }
    };

    {
        const float h0 = halo_load(0);
        stage(0, tile[0]);
        halo_write(tile[0], h0);
    }
    __syncthreads();   // also publishes wlds

#pragma unroll 1
    for (int i = 0; i < CIN; i += 2) {
        const float hB = halo_load(i + 1);    // issue global loads for ci+1
        stage(i + 1, tile[1]);                //   (DMA in flight across compute)
        compute(i, tile[0]);
        halo_write(tile[1], hB);              // latency hidden under compute
        __syncthreads();                      // tile[1] ready

        const bool more = (i + 2 < CIN);
        float hA = 0.f;
        if (more) { hA = halo_load(i + 2); stage(i + 2, tile[0]); }
        compute(i + 1, tile[1]);
        if (more) halo_write(tile[0], hA);
        __syncthreads();
    }

    // write-once streaming output: nontemporal keeps x resident in L2
    float* on = out + (size_t)(n * COUT) * (HH * WW) + (size_t)h * WW + c0 + tx;
#pragma unroll
    for (int o = 0; o < COUT; ++o)
#pragma unroll
        for (int p = 0; p < 4; ++p)
            __builtin_nontemporal_store(acc[o][p], &on[(size_t)o * (HH * WW) + p * 64]);
}

extern "C" void kernel_launch(void* const* d_in, const int* in_sizes, int n_in,
                              void* d_out, int out_size, void* d_ws, size_t ws_size,
                              hipStream_t stream) {
    const float* x  = (const float*)d_in[0];   // [16,16,512,512] fp32
    const float* fw = (const float*)d_in[1];   // [16,16,5] fp32
    float* out = (float*)d_out;                // [16,16,512,512] fp32

    dim3 block(64, 4, 1);
    dim3 grid(4096, 1, 1);   // (2 w-tiles) x (128 h-tiles) x (16 n), swizzled in-kernel
    hipLaunchKernelGGL(diag_conv_kernel, grid, block, 0, stream, x, fw, out);
}